// Round 13
// baseline (235.705 us; speedup 1.0000x reference)
//
#include <hip/hip_runtime.h>
#include <string.h>

// ---------------- problem constants ----------------
#define T_LEN   809
#define DD      304
#define EE      300
#define LQ      30
#define NCAND   12824      // candidates per batch
#define NPAD    12928      // 101 * 128 (padded rows per batch)
#define CIN     1212
#define H1      1024
#define H2      512
#define BATCH   4
#define MROWS_F (BATCH * NPAD)          // 51712 fused rows
#define KS      320                     // 304 padded to mult of 32 (scan-GEMM K)
#define TPAD    3328                    // 26 * 128

// mega-prep block ranges
#define MP_SCAN0   0          // 416 blocks  (208 virtual x 2 d-chunks)
#define MP_W1      416        // 3840 blocks (3072*320/256)
#define MP_W2      4256       // 2048 blocks (512*1024/256)
#define MP_BIAS2   6304       // 2 blocks
#define MP_BASE    6306       // 1024 blocks (4 b x 256 jg)
#define MP_TOTAL   7330

// alpha^(span+1), span in [0,16)
__device__ __constant__ float c_coef[16] = {
  0.9f, 0.81f, 0.729f, 0.6561f, 0.59049f, 0.531441f, 0.4782969f, 0.43046721f,
  0.387420489f, 0.3486784401f, 0.31381059609f, 0.282429536481f,
  0.2541865828329f, 0.22876792454961f, 0.205891132094649f, 0.1853020188851841f
};

__device__ __forceinline__ unsigned short f2bf(float f) {
  unsigned int u = __float_as_uint(f);
  u += 0x7fffu + ((u >> 16) & 1u);          // round-to-nearest-even
  return (unsigned short)(u >> 16);
}
__device__ __forceinline__ float bf2f(unsigned int h) {
  return __uint_as_float(h << 16);
}

typedef const __attribute__((address_space(1))) unsigned int GU32;
typedef __attribute__((address_space(3))) unsigned int LU32;
__device__ __forceinline__ void async16(const unsigned short* g, unsigned short* l) {
  __builtin_amdgcn_global_load_lds((GU32*)g, (LU32*)l, 16, 0, 0);
}

// ---------------- mega prep: scan + W1 split + W2 fold + bias2 + baseW ----------------
__global__ __launch_bounds__(256) void k_prep(const float* __restrict__ doc,
                                              const float* __restrict__ qe,
                                              const float* __restrict__ W1,
                                              const float* __restrict__ g1,
                                              const float* __restrict__ b1,
                                              const float* __restrict__ m1,
                                              const float* __restrict__ v1,
                                              const float* __restrict__ W2,
                                              const float* __restrict__ g2,
                                              const float* __restrict__ b2,
                                              const float* __restrict__ m2,
                                              const float* __restrict__ v2,
                                              unsigned short* __restrict__ Fz,
                                              unsigned short* __restrict__ Rz,
                                              unsigned short* __restrict__ Wlc,
                                              unsigned short* __restrict__ Wr,
                                              unsigned short* __restrict__ W2b,
                                              float* __restrict__ bias2,
                                              float* __restrict__ baseW)
{
  __shared__ float qs[EE];
  const int vb  = blockIdx.x;
  const int tid = threadIdx.x;

  if (vb < MP_W1) {
    // ---- scan section: vb in [0,416), 96-step lookback (alpha^96 ~ 4e-5) ----
    const int dchunk = vb & 1;
    const int rest   = vb >> 1;            // 0..207
    const int tchunk = rest % 26;
    const int b      = (rest / 26) & 3;
    const int dir    = rest / 104;
    const int d  = dchunk * 256 + tid;     // 0..511 (valid < 320)
    const int t0 = tchunk * 32;
    if (dir == 0) {
      if (tchunk == 0 && d < KS) Fz[((size_t)b * 810) * KS + d] = 0;   // zero row
      if (d >= DD) return;
      const float* db = doc + (size_t)b * T_LEN * DD + d;
      int start = t0 - 96; if (start < 0) start = 0;
      int end = t0 + 31; if (end > T_LEN - 1) end = T_LEN - 1;
      float s = 0.f;
      for (int t = start; t <= end; ++t) {
        s = fmaf(0.9f, s, db[(size_t)t * DD]);
        if (t >= t0) Fz[((size_t)b * 810 + 1 + t) * KS + d] = f2bf(s);
      }
    } else {
      if (tchunk == 0 && d < KS) Rz[((size_t)b * 810 + 809) * KS + d] = 0;  // zero row
      if (d >= DD) return;
      const float* db = doc + (size_t)b * T_LEN * DD + d;
      int t1 = t0 + 31; if (t1 > T_LEN - 1) t1 = T_LEN - 1;
      int start = t1 + 96; if (start > T_LEN - 1) start = T_LEN - 1;
      float s = 0.f;
      for (int t = start; t >= t0; --t) {
        s = fmaf(0.9f, s, db[(size_t)t * DD]);
        if (t <= t1) Rz[((size_t)b * 810 + t) * KS + d] = f2bf(s);
      }
    }
  } else if (vb < MP_W2) {
    // ---- W1 split: flat over 3072 x 320 ----
    const int e = (vb - MP_W1) * 256 + tid;
    const int j = e / KS;                  // 0..3071
    const int k = e - j * KS;              // 0..319
    int jj, koff; unsigned short* dst; size_t idx;
    if (j < 1024)      { jj = j;        koff = k;       dst = Wlc; idx = (size_t)j * KS + k; }
    else if (j < 2048) { jj = j - 1024; koff = 304 + k; dst = Wlc; idx = (size_t)j * KS + k; }
    else               { jj = j - 2048; koff = 608 + k; dst = Wr;  idx = (size_t)(j - 2048) * KS + k; }
    float w = 0.f;
    if (k < 304) w = W1[(size_t)jj * CIN + koff] * g1[jj] * rsqrtf(v1[jj] + 1e-5f);
    dst[idx] = f2bf(w);
  } else if (vb < MP_BIAS2) {
    // ---- W2 fold: flat over 512 x 1024 ----
    const int e = (vb - MP_W2) * 256 + tid;
    const int j = e >> 10;
    const int k = e & 1023;
    const float w = W2[(size_t)j * H1 + k] * g2[j] * rsqrtf(v2[j] + 1e-5f);
    W2b[(size_t)j * H1 + k] = f2bf(w);
  } else if (vb < MP_BASE) {
    // ---- bias2 ----
    const int i = (vb - MP_BIAS2) * 256 + tid;
    if (i < H2) {
      const float s = g2[i] * rsqrtf(v2[i] + 1e-5f);
      bias2[i] = b2[i] - m2[i] * s;
    }
  } else {
    // ---- baseW (2048-wide, cand half zero): 1024 blocks = (b, jg) ----
    const int flat = vb - MP_BASE;
    const int b  = flat >> 8;
    const int jg = flat & 255;
    const float* q = qe + (size_t)b * LQ * EE;
    for (int k = tid; k < EE; k += 256) {
      float s = 0.f;
      for (int t = 0; t < LQ; ++t) s = fmaf(s, 0.9f, q[(size_t)t * EE + k]);
      qs[k] = s;
    }
    __syncthreads();
    const int wv   = tid >> 6;
    const int lane = tid & 63;
    const int j = jg * 4 + wv;             // 0..1023
    const float* w = W1 + (size_t)j * CIN + 912;
    float acc = 0.f;
    for (int k = lane; k < EE; k += 64) acc = fmaf(qs[k], w[k], acc);
    #pragma unroll
    for (int off = 32; off; off >>= 1) acc += __shfl_down(acc, off);
    if (lane == 0) {
      const float sc = g1[j] * rsqrtf(v1[j] + 1e-5f);
      baseW[(size_t)b * 2048 + j]        = b1[j] - m1[j] * sc + acc * sc;
      baseW[(size_t)b * 2048 + 1024 + j] = 0.f;
    }
  }
}

// ---------------- GEMM machinery ----------------
typedef __attribute__((ext_vector_type(8))) short frag8;
typedef __attribute__((ext_vector_type(4))) float f32x4;

// 128x128 tile, BK=32, 4 waves of 64x64.  Chunk-swizzled LDS (conflict-free).
#define GEMM_KLOOP(A_, B_, K_)                                                   \
  __shared__ __align__(16) unsigned short As[128 * 32];                          \
  __shared__ __align__(16) unsigned short Bs[128 * 32];                          \
  const int tid  = threadIdx.x;                                                  \
  const int lane = tid & 63;                                                     \
  const int wv   = tid >> 6;                                                     \
  const int wm   = wv & 1, wn = wv >> 1;                                         \
  const int lr = lane >> 2;                                                      \
  const int lc = lane & 3;                                                       \
  const int sc = lc ^ ((lr >> 1) & 3);                                           \
  const unsigned short* gA = A_ + ((size_t)bm * 128 + wv * 32 + lr) * K_ + sc * 8; \
  const unsigned short* gB = B_ + ((size_t)bn * 128 + wv * 32 + lr) * K_ + sc * 8; \
  const size_t row16 = (size_t)16 * K_;                                          \
  unsigned short* lA0 = &As[wv * 1024];                                          \
  unsigned short* lB0 = &Bs[wv * 1024];                                          \
  f32x4 acc[4][4];                                                               \
  _Pragma("unroll")                                                              \
  for (int i = 0; i < 4; ++i)                                                    \
    _Pragma("unroll")                                                            \
    for (int j = 0; j < 4; ++j) acc[i][j] = (f32x4){0.f, 0.f, 0.f, 0.f};         \
  const int arow = lane & 15;                                                    \
  const int pg   = (lane >> 4) ^ ((arow >> 1) & 3);                              \
  const int aoff = (wm * 64 + arow) * 32 + pg * 8;                               \
  const int boff = (wn * 64 + arow) * 32 + pg * 8;                               \
  for (int kc = 0; kc < K_; kc += 32) {                                          \
    __syncthreads();                                                             \
    async16(gA + kc,         lA0);                                               \
    async16(gA + kc + row16, lA0 + 512);                                         \
    async16(gB + kc,         lB0);                                               \
    async16(gB + kc + row16, lB0 + 512);                                         \
    __syncthreads();                                                             \
    frag8 a[4], b[4];                                                            \
    _Pragma("unroll")                                                            \
    for (int i = 0; i < 4; ++i) a[i] = *(const frag8*)&As[aoff + i * 512];       \
    _Pragma("unroll")                                                            \
    for (int i = 0; i < 4; ++i) b[i] = *(const frag8*)&Bs[boff + i * 512];       \
    _Pragma("unroll")                                                            \
    for (int i = 0; i < 4; ++i)                                                  \
      _Pragma("unroll")                                                          \
      for (int j = 0; j < 4; ++j)                                                \
        acc[i][j] = __builtin_amdgcn_mfma_f32_16x16x32_bf16(a[i], b[j], acc[i][j], 0, 0, 0); \
  }

// ---------------- fused U-table GEMMs (UF and UR in one launch), bf16 out ----------------
__global__ __launch_bounds__(256, 4) void k_ugemm(const unsigned short* __restrict__ Fz,
                                                  const unsigned short* __restrict__ Wlc,
                                                  const unsigned short* __restrict__ Rz,
                                                  const unsigned short* __restrict__ Wr,
                                                  const float* __restrict__ baseW,
                                                  unsigned short* __restrict__ UF,
                                                  unsigned short* __restrict__ UR)
{
  int bx = blockIdx.x;
  const int isUF = (bx < 416);
  const unsigned short *Ap, *Bp; unsigned short* Cp; int bn, bm, Nout;
  if (isUF) { Ap = Fz; Bp = Wlc; Cp = UF; bn = bx & 15; bm = bx >> 4; Nout = 2048; }
  else { bx -= 416; Ap = Rz; Bp = Wr; Cp = UR; bn = bx & 7; bm = bx >> 3; Nout = 1024; }
  GEMM_KLOOP(Ap, Bp, KS)
  const int crow0 = bm * 128 + wm * 64 + ((lane >> 4) << 2);
  const int ccol0 = bn * 128 + wn * 64 + arow;
  #pragma unroll
  for (int i = 0; i < 4; ++i)
    #pragma unroll
    for (int j = 0; j < 4; ++j) {
      const int col = ccol0 + j * 16;
      #pragma unroll
      for (int r = 0; r < 4; ++r) {
        const int row = crow0 + i * 16 + r;
        float v = acc[i][j][r];
        if (isUF) {
          int bb = row / 810; if (bb > 3) bb = 3;   // clamp padded rows
          v += baseW[(size_t)bb * 2048 + col];
        }
        Cp[(size_t)row * Nout + col] = f2bf(v);
      }
    }
}

// ---------------- combine: h1 = relu(UL'[s] + UC[e+1] - coef*UC[s] + UR[e+1]) ----------------
__global__ __launch_bounds__(512) void k_combine(const unsigned short* __restrict__ UF,
                                                 const unsigned short* __restrict__ UR,
                                                 unsigned short* __restrict__ h1)
{
  __shared__ float s_ul[1024];
  __shared__ float s_ucs[1024];
  const int flat = (blockIdx.x & 7) * 405 + (blockIdx.x >> 3);
  if (flat >= BATCH * T_LEN) return;
  const int b = flat / T_LEN;
  const int s = flat - b * T_LEN;
  const int oct = threadIdx.x >> 6;      // 0..7: eight span-rows in flight
  const int t = threadIdx.x & 63;        // 16-elem slice
  const size_t rs = (size_t)b * 810 + s;
  const int e0 = t * 16;

  {
    const unsigned int u = *(const unsigned int*)(UF + rs * 2048 + threadIdx.x * 2);
    const unsigned int c = *(const unsigned int*)(UF + rs * 2048 + 1024 + threadIdx.x * 2);
    s_ul[threadIdx.x * 2]      = bf2f(u & 0xffff);
    s_ul[threadIdx.x * 2 + 1]  = bf2f(u >> 16);
    s_ucs[threadIdx.x * 2]     = bf2f(c & 0xffff);
    s_ucs[threadIdx.x * 2 + 1] = bf2f(c >> 16);
  }
  __syncthreads();

  float ul[16], ucs[16];
  #pragma unroll
  for (int k = 0; k < 4; ++k) {
    const float4 a = *(const float4*)&s_ul[e0 + k * 4];
    const float4 c = *(const float4*)&s_ucs[e0 + k * 4];
    ul[4*k] = a.x; ul[4*k+1] = a.y; ul[4*k+2] = a.z; ul[4*k+3] = a.w;
    ucs[4*k] = c.x; ucs[4*k+1] = c.y; ucs[4*k+2] = c.z; ucs[4*k+3] = c.w;
  }

  const int nspan = min(16, T_LEN - s);
  int r0;
  if (s < 794) r0 = s * 16;
  else { const int d = s - 794; r0 = 12704 + 15 * d - (d * (d - 1)) / 2; }

  #pragma unroll
  for (int sp = 0; sp < 16; sp += 8) {
    const int row = sp + oct;
    if (row < nspan) {
      const size_t re = rs + row + 1;
      const uint4 e0v = *(const uint4*)(UF + re * 2048 + 1024 + e0);
      const uint4 e1v = *(const uint4*)(UF + re * 2048 + 1024 + e0 + 8);
      const uint4 r0v = *(const uint4*)(UR + re * 1024 + e0);
      const uint4 r1v = *(const uint4*)(UR + re * 1024 + e0 + 8);
      const float c = c_coef[row];
      const unsigned int* pe0 = (const unsigned int*)&e0v;
      const unsigned int* pe1 = (const unsigned int*)&e1v;
      const unsigned int* pr0 = (const unsigned int*)&r0v;
      const unsigned int* pr1 = (const unsigned int*)&r1v;
      unsigned int o[8];
      #pragma unroll
      for (int i = 0; i < 4; ++i) {
        float xlo = ul[2*i]   + bf2f(pe0[i] & 0xffff) - c * ucs[2*i]   + bf2f(pr0[i] & 0xffff);
        float xhi = ul[2*i+1] + bf2f(pe0[i] >> 16)    - c * ucs[2*i+1] + bf2f(pr0[i] >> 16);
        xlo = xlo > 0.f ? xlo : 0.f;
        xhi = xhi > 0.f ? xhi : 0.f;
        o[i] = (unsigned int)f2bf(xlo) | ((unsigned int)f2bf(xhi) << 16);
        float ylo = ul[8+2*i]   + bf2f(pe1[i] & 0xffff) - c * ucs[8+2*i]   + bf2f(pr1[i] & 0xffff);
        float yhi = ul[8+2*i+1] + bf2f(pe1[i] >> 16)    - c * ucs[8+2*i+1] + bf2f(pr1[i] >> 16);
        ylo = ylo > 0.f ? ylo : 0.f;
        yhi = yhi > 0.f ? yhi : 0.f;
        o[4 + i] = (unsigned int)f2bf(ylo) | ((unsigned int)f2bf(yhi) << 16);
      }
      unsigned short* dst = h1 + ((size_t)b * NPAD + r0 + row) * H1 + e0;
      *(uint4*)dst = *(const uint4*)&o[0];
      *(uint4*)(dst + 8) = *(const uint4*)&o[4];
    }
  }
}

// ---------------- GEMM2 + fused W3: 256x128 tile, 8 waves, less staging per MFMA ----------------
// L2-staging-bound fix: (1/M + 1/N) smaller -> 24KB staged per iter for 8 waves
// (was 16KB for 4).  Per-wave tile stays 64x64 (acc 64 regs, 124 total, 4 waves/SIMD).
__global__ __launch_bounds__(512, 4) void k_gemm2p(const unsigned short* __restrict__ A,
                                                   const unsigned short* __restrict__ W2b,
                                                   const float* __restrict__ bias,
                                                   const float* __restrict__ W3,
                                                   float* __restrict__ P)
{
  const int global = blockIdx.x * 101 + blockIdx.y;   // xcd-contiguous range, bn fastest
  const int bm = global >> 2;          // 0..201 (256-row tiles)
  const int bn = global & 3;           // 0..3   (128-col tiles)
  __shared__ __align__(16) unsigned short As[256 * 32];
  __shared__ __align__(16) unsigned short Bs[128 * 32];
  __shared__ float red[4][4][4][4][2];                // [wm][i][r][grp][{p0,p1}]
  const int tid  = threadIdx.x;
  const int lane = tid & 63;
  const int wv   = tid >> 6;           // 0..7
  const int wm   = wv >> 1;            // 0..3 (64-row band)
  const int wn   = wv & 1;             // 0..1 (64-col band)
  const int lr = lane >> 2;            // 0..15
  const int lc = lane & 3;
  const int sc = lc ^ ((lr >> 1) & 3);
  // staging: wave wv stages A rows [wv*32, wv*32+32) and B rows [wv*16, wv*16+16)
  const unsigned short* gA = A   + ((size_t)bm * 256 + wv * 32 + lr) * H1 + sc * 8;
  const unsigned short* gB = W2b + ((size_t)bn * 128 + wv * 16 + lr) * H1 + sc * 8;
  const size_t row16 = (size_t)16 * H1;
  unsigned short* lA0 = &As[wv * 1024];
  unsigned short* lB0 = &Bs[wv * 512];

  f32x4 acc[4][4];
  #pragma unroll
  for (int i = 0; i < 4; ++i)
    #pragma unroll
    for (int j = 0; j < 4; ++j) acc[i][j] = (f32x4){0.f, 0.f, 0.f, 0.f};

  const int arow = lane & 15;
  const int pg   = (lane >> 4) ^ ((arow >> 1) & 3);
  const int aoff = (wm * 64 + arow) * 32 + pg * 8;
  const int boff = (wn * 64 + arow) * 32 + pg * 8;

  for (int kc = 0; kc < H1; kc += 32) {
    __syncthreads();
    async16(gA + kc,         lA0);
    async16(gA + kc + row16, lA0 + 512);
    async16(gB + kc,         lB0);
    __syncthreads();
    frag8 a[4], b[4];
    #pragma unroll
    for (int i = 0; i < 4; ++i) a[i] = *(const frag8*)&As[aoff + i * 512];
    #pragma unroll
    for (int i = 0; i < 4; ++i) b[i] = *(const frag8*)&Bs[boff + i * 512];
    #pragma unroll
    for (int i = 0; i < 4; ++i)
      #pragma unroll
      for (int j = 0; j < 4; ++j)
        acc[i][j] = __builtin_amdgcn_mfma_f32_16x16x32_bf16(a[i], b[j], acc[i][j], 0, 0, 0);
  }

  const int ccol0 = bn * 128 + wn * 64 + arow;
  float bj[4], w0[4], w1[4];
  #pragma unroll
  for (int j = 0; j < 4; ++j) {
    const int col = ccol0 + j * 16;
    bj[j] = bias[col];
    w0[j] = W3[col];
    w1[j] = W3[H2 + col];
  }
  float p0[4][4], p1[4][4];
  #pragma unroll
  for (int i = 0; i < 4; ++i)
    #pragma unroll
    for (int r = 0; r < 4; ++r) {
      float q0 = 0.f, q1 = 0.f;
      #pragma unroll
      for (int j = 0; j < 4; ++j) {
        float v = acc[i][j][r] + bj[j];
        v = v > 0.f ? v : 0.f;
        q0 = fmaf(v, w0[j], q0);
        q1 = fmaf(v, w1[j], q1);
      }
      #pragma unroll
      for (int m = 1; m < 16; m <<= 1) {
        q0 += __shfl_xor(q0, m);
        q1 += __shfl_xor(q1, m);
      }
      p0[i][r] = q0; p1[i][r] = q1;
    }

  const int grp = lane >> 4;
  if (wn == 1 && arow == 0) {
    #pragma unroll
    for (int i = 0; i < 4; ++i)
      #pragma unroll
      for (int r = 0; r < 4; ++r) {
        red[wm][i][r][grp][0] = p0[i][r];
        red[wm][i][r][grp][1] = p1[i][r];
      }
  }
  __syncthreads();
  if (wn == 0 && arow == 0) {
    #pragma unroll
    for (int i = 0; i < 4; ++i)
      #pragma unroll
      for (int r = 0; r < 4; ++r) {
        const size_t row = (size_t)bm * 256 + wm * 64 + grp * 4 + i * 16 + r;
        P[row * 8 + bn * 2 + 0] = p0[i][r] + red[wm][i][r][grp][0];
        P[row * 8 + bn * 2 + 1] = p1[i][r] + red[wm][i][r][grp][1];
      }
  }
}

// ---------------- final: sum 4 bn-partials per row -> out ----------------
__global__ __launch_bounds__(256) void k_fin(const float* __restrict__ P, float* __restrict__ out)
{
  const int row = blockIdx.x * 256 + threadIdx.x;
  if (row >= MROWS_F) return;
  const int b = row / NPAD;
  const int rr = row - b * NPAD;
  if (rr >= NCAND) return;
  const float4 pa = ((const float4*)P)[row * 2];
  const float4 pb = ((const float4*)P)[row * 2 + 1];
  float* o = out + ((size_t)b * NCAND + rr) * 2;
  o[0] = pa.x + pa.z + pb.x + pb.z;
  o[1] = pa.y + pa.w + pb.y + pb.w;
}

// ---------------- launch ----------------
extern "C" void kernel_launch(void* const* d_in, const int* in_sizes, int n_in,
                              void* d_out, int out_size, void* d_ws, size_t ws_size,
                              hipStream_t stream)
{
  const float* doc = (const float*)d_in[0];
  const float* qe  = (const float*)d_in[1];
  const float* W1  = (const float*)d_in[2];
  const float* g1  = (const float*)d_in[3];
  const float* b1  = (const float*)d_in[4];
  const float* m1  = (const float*)d_in[5];
  const float* v1  = (const float*)d_in[6];
  const float* W2  = (const float*)d_in[7];
  const float* g2  = (const float*)d_in[8];
  const float* b2  = (const float*)d_in[9];
  const float* m2  = (const float*)d_in[10];
  const float* v2  = (const float*)d_in[11];
  const float* W3  = (const float*)d_in[12];
  float* out = (float*)d_out;

  char* ws = (char*)d_ws;
  size_t off = 0;
  auto alloc = [&](size_t bytes) -> void* {
    void* p = ws + off;
    off = (off + bytes + 255) & ~(size_t)255;
    return p;
  };
  unsigned short* Fz    = (unsigned short*)alloc((size_t)TPAD * KS * 2);
  unsigned short* Rz    = (unsigned short*)alloc((size_t)TPAD * KS * 2);
  unsigned short* Wlc   = (unsigned short*)alloc((size_t)2048 * KS * 2);
  unsigned short* Wr    = (unsigned short*)alloc((size_t)1024 * KS * 2);
  unsigned short* W2b   = (unsigned short*)alloc((size_t)H2 * H1 * 2);
  float*          bias2 = (float*)alloc((size_t)H2 * 4);
  float*          baseW = (float*)alloc((size_t)BATCH * 2048 * 4);
  unsigned short* UF    = (unsigned short*)alloc((size_t)TPAD * 2048 * 2);
  unsigned short* UR    = (unsigned short*)alloc((size_t)TPAD * 1024 * 2);
  unsigned short* h1    = (unsigned short*)alloc((size_t)MROWS_F * H1 * 2);
  float*          P     = (float*)alloc((size_t)MROWS_F * 8 * 4);
  (void)ws_size;

  // 1. fused prep (scan + qf/baseW + weight folds)
  k_prep<<<dim3(MP_TOTAL), 256, 0, stream>>>(doc, qe, W1, g1, b1, m1, v1,
                                             W2, g2, b2, m2, v2,
                                             Fz, Rz, Wlc, Wr, W2b, bias2, baseW);
  // 2. fused U-table GEMMs (base folded into UF)
  k_ugemm<<<dim3(416 + 208), 256, 0, stream>>>(Fz, Wlc, Rz, Wr, baseW, UF, UR);
  // 3. gather-combine -> h1 (bf16)
  k_combine<<<dim3(8 * 405), 512, 0, stream>>>(UF, UR, h1);
  // 4. GEMM2 with fused W3 partials (256x128 tile, 8 waves)
  k_gemm2p<<<dim3(8, 101), 512, 0, stream>>>(h1, W2b, bias2, W3, P);
  // 5. reduce partials -> out
  k_fin<<<dim3((MROWS_F + 255) / 256), 256, 0, stream>>>(P, out);
}

// Round 14
// 227.040 us; speedup vs baseline: 1.0382x; 1.0382x over previous
//
#include <hip/hip_runtime.h>
#include <string.h>

// ---------------- problem constants ----------------
#define T_LEN   809
#define DD      304
#define EE      300
#define LQ      30
#define NCAND   12824      // candidates per batch
#define NPAD    12928      // 101 * 128 (padded rows per batch)
#define CIN     1212
#define H1      1024
#define H2      512
#define BATCH   4
#define MROWS_F (BATCH * NPAD)          // 51712 fused rows
#define KS      320                     // 304 padded to mult of 32 (scan-GEMM K)
#define TPAD    3328                    // 26 * 128

// mega-prep block ranges
#define MP_SCAN0   0          // 416 blocks  (208 virtual x 2 d-chunks)
#define MP_W1      416        // 3840 blocks (3072*320/256)
#define MP_W2      4256       // 2048 blocks (512*1024/256)
#define MP_BIAS2   6304       // 2 blocks
#define MP_BASE    6306       // 1024 blocks (4 b x 256 jg)
#define MP_TOTAL   7330

// alpha^(span+1), span in [0,16)
__device__ __constant__ float c_coef[16] = {
  0.9f, 0.81f, 0.729f, 0.6561f, 0.59049f, 0.531441f, 0.4782969f, 0.43046721f,
  0.387420489f, 0.3486784401f, 0.31381059609f, 0.282429536481f,
  0.2541865828329f, 0.22876792454961f, 0.205891132094649f, 0.1853020188851841f
};

__device__ __forceinline__ unsigned short f2bf(float f) {
  unsigned int u = __float_as_uint(f);
  u += 0x7fffu + ((u >> 16) & 1u);          // round-to-nearest-even
  return (unsigned short)(u >> 16);
}
__device__ __forceinline__ float bf2f(unsigned int h) {
  return __uint_as_float(h << 16);
}

typedef const __attribute__((address_space(1))) unsigned int GU32;
typedef __attribute__((address_space(3))) unsigned int LU32;
__device__ __forceinline__ void async16(const unsigned short* g, unsigned short* l) {
  __builtin_amdgcn_global_load_lds((GU32*)g, (LU32*)l, 16, 0, 0);
}

// ---------------- mega prep: scan + W1 split + W2 fold + bias2 + baseW ----------------
__global__ __launch_bounds__(256) void k_prep(const float* __restrict__ doc,
                                              const float* __restrict__ qe,
                                              const float* __restrict__ W1,
                                              const float* __restrict__ g1,
                                              const float* __restrict__ b1,
                                              const float* __restrict__ m1,
                                              const float* __restrict__ v1,
                                              const float* __restrict__ W2,
                                              const float* __restrict__ g2,
                                              const float* __restrict__ b2,
                                              const float* __restrict__ m2,
                                              const float* __restrict__ v2,
                                              unsigned short* __restrict__ Fz,
                                              unsigned short* __restrict__ Rz,
                                              unsigned short* __restrict__ Wlc,
                                              unsigned short* __restrict__ Wr,
                                              unsigned short* __restrict__ W2b,
                                              float* __restrict__ bias2,
                                              float* __restrict__ baseW)
{
  __shared__ float qs[EE];
  const int vb  = blockIdx.x;
  const int tid = threadIdx.x;

  if (vb < MP_W1) {
    // ---- scan section: vb in [0,416), 96-step lookback (alpha^96 ~ 4e-5) ----
    const int dchunk = vb & 1;
    const int rest   = vb >> 1;            // 0..207
    const int tchunk = rest % 26;
    const int b      = (rest / 26) & 3;
    const int dir    = rest / 104;
    const int d  = dchunk * 256 + tid;     // 0..511 (valid < 320)
    const int t0 = tchunk * 32;
    if (dir == 0) {
      if (tchunk == 0 && d < KS) Fz[((size_t)b * 810) * KS + d] = 0;   // zero row
      if (d >= DD) return;
      const float* db = doc + (size_t)b * T_LEN * DD + d;
      int start = t0 - 96; if (start < 0) start = 0;
      int end = t0 + 31; if (end > T_LEN - 1) end = T_LEN - 1;
      float s = 0.f;
      for (int t = start; t <= end; ++t) {
        s = fmaf(0.9f, s, db[(size_t)t * DD]);
        if (t >= t0) Fz[((size_t)b * 810 + 1 + t) * KS + d] = f2bf(s);
      }
    } else {
      if (tchunk == 0 && d < KS) Rz[((size_t)b * 810 + 809) * KS + d] = 0;  // zero row
      if (d >= DD) return;
      const float* db = doc + (size_t)b * T_LEN * DD + d;
      int t1 = t0 + 31; if (t1 > T_LEN - 1) t1 = T_LEN - 1;
      int start = t1 + 96; if (start > T_LEN - 1) start = T_LEN - 1;
      float s = 0.f;
      for (int t = start; t >= t0; --t) {
        s = fmaf(0.9f, s, db[(size_t)t * DD]);
        if (t <= t1) Rz[((size_t)b * 810 + t) * KS + d] = f2bf(s);
      }
    }
  } else if (vb < MP_W2) {
    // ---- W1 split: flat over 3072 x 320 ----
    const int e = (vb - MP_W1) * 256 + tid;
    const int j = e / KS;                  // 0..3071
    const int k = e - j * KS;              // 0..319
    int jj, koff; unsigned short* dst; size_t idx;
    if (j < 1024)      { jj = j;        koff = k;       dst = Wlc; idx = (size_t)j * KS + k; }
    else if (j < 2048) { jj = j - 1024; koff = 304 + k; dst = Wlc; idx = (size_t)j * KS + k; }
    else               { jj = j - 2048; koff = 608 + k; dst = Wr;  idx = (size_t)(j - 2048) * KS + k; }
    float w = 0.f;
    if (k < 304) w = W1[(size_t)jj * CIN + koff] * g1[jj] * rsqrtf(v1[jj] + 1e-5f);
    dst[idx] = f2bf(w);
  } else if (vb < MP_BIAS2) {
    // ---- W2 fold: flat over 512 x 1024 ----
    const int e = (vb - MP_W2) * 256 + tid;
    const int j = e >> 10;
    const int k = e & 1023;
    const float w = W2[(size_t)j * H1 + k] * g2[j] * rsqrtf(v2[j] + 1e-5f);
    W2b[(size_t)j * H1 + k] = f2bf(w);
  } else if (vb < MP_BASE) {
    // ---- bias2 ----
    const int i = (vb - MP_BIAS2) * 256 + tid;
    if (i < H2) {
      const float s = g2[i] * rsqrtf(v2[i] + 1e-5f);
      bias2[i] = b2[i] - m2[i] * s;
    }
  } else {
    // ---- baseW (2048-wide, cand half zero): 1024 blocks = (b, jg) ----
    const int flat = vb - MP_BASE;
    const int b  = flat >> 8;
    const int jg = flat & 255;
    const float* q = qe + (size_t)b * LQ * EE;
    for (int k = tid; k < EE; k += 256) {
      float s = 0.f;
      for (int t = 0; t < LQ; ++t) s = fmaf(s, 0.9f, q[(size_t)t * EE + k]);
      qs[k] = s;
    }
    __syncthreads();
    const int wv   = tid >> 6;
    const int lane = tid & 63;
    const int j = jg * 4 + wv;             // 0..1023
    const float* w = W1 + (size_t)j * CIN + 912;
    float acc = 0.f;
    for (int k = lane; k < EE; k += 64) acc = fmaf(qs[k], w[k], acc);
    #pragma unroll
    for (int off = 32; off; off >>= 1) acc += __shfl_down(acc, off);
    if (lane == 0) {
      const float sc = g1[j] * rsqrtf(v1[j] + 1e-5f);
      baseW[(size_t)b * 2048 + j]        = b1[j] - m1[j] * sc + acc * sc;
      baseW[(size_t)b * 2048 + 1024 + j] = 0.f;
    }
  }
}

// ---------------- GEMM machinery ----------------
typedef __attribute__((ext_vector_type(8))) short frag8;
typedef __attribute__((ext_vector_type(4))) float f32x4;

// 128x128 tile, BK=32, 4 waves of 64x64.  Chunk-swizzled LDS (conflict-free).
#define GEMM_KLOOP(A_, B_, K_)                                                   \
  __shared__ __align__(16) unsigned short As[128 * 32];                          \
  __shared__ __align__(16) unsigned short Bs[128 * 32];                          \
  const int tid  = threadIdx.x;                                                  \
  const int lane = tid & 63;                                                     \
  const int wv   = tid >> 6;                                                     \
  const int wm   = wv & 1, wn = wv >> 1;                                         \
  const int lr = lane >> 2;                                                      \
  const int lc = lane & 3;                                                       \
  const int sc = lc ^ ((lr >> 1) & 3);                                           \
  const unsigned short* gA = A_ + ((size_t)bm * 128 + wv * 32 + lr) * K_ + sc * 8; \
  const unsigned short* gB = B_ + ((size_t)bn * 128 + wv * 32 + lr) * K_ + sc * 8; \
  const size_t row16 = (size_t)16 * K_;                                          \
  unsigned short* lA0 = &As[wv * 1024];                                          \
  unsigned short* lB0 = &Bs[wv * 1024];                                          \
  f32x4 acc[4][4];                                                               \
  _Pragma("unroll")                                                              \
  for (int i = 0; i < 4; ++i)                                                    \
    _Pragma("unroll")                                                            \
    for (int j = 0; j < 4; ++j) acc[i][j] = (f32x4){0.f, 0.f, 0.f, 0.f};         \
  const int arow = lane & 15;                                                    \
  const int pg   = (lane >> 4) ^ ((arow >> 1) & 3);                              \
  const int aoff = (wm * 64 + arow) * 32 + pg * 8;                               \
  const int boff = (wn * 64 + arow) * 32 + pg * 8;                               \
  for (int kc = 0; kc < K_; kc += 32) {                                          \
    __syncthreads();                                                             \
    async16(gA + kc,         lA0);                                               \
    async16(gA + kc + row16, lA0 + 512);                                         \
    async16(gB + kc,         lB0);                                               \
    async16(gB + kc + row16, lB0 + 512);                                         \
    __syncthreads();                                                             \
    frag8 a[4], b[4];                                                            \
    _Pragma("unroll")                                                            \
    for (int i = 0; i < 4; ++i) a[i] = *(const frag8*)&As[aoff + i * 512];       \
    _Pragma("unroll")                                                            \
    for (int i = 0; i < 4; ++i) b[i] = *(const frag8*)&Bs[boff + i * 512];       \
    _Pragma("unroll")                                                            \
    for (int i = 0; i < 4; ++i)                                                  \
      _Pragma("unroll")                                                          \
      for (int j = 0; j < 4; ++j)                                                \
        acc[i][j] = __builtin_amdgcn_mfma_f32_16x16x32_bf16(a[i], b[j], acc[i][j], 0, 0, 0); \
  }

// ---------------- fused U-table GEMMs (UF and UR in one launch), bf16 out ----------------
__global__ __launch_bounds__(256, 4) void k_ugemm(const unsigned short* __restrict__ Fz,
                                                  const unsigned short* __restrict__ Wlc,
                                                  const unsigned short* __restrict__ Rz,
                                                  const unsigned short* __restrict__ Wr,
                                                  const float* __restrict__ baseW,
                                                  unsigned short* __restrict__ UF,
                                                  unsigned short* __restrict__ UR)
{
  int bx = blockIdx.x;
  const int isUF = (bx < 416);
  const unsigned short *Ap, *Bp; unsigned short* Cp; int bn, bm, Nout;
  if (isUF) { Ap = Fz; Bp = Wlc; Cp = UF; bn = bx & 15; bm = bx >> 4; Nout = 2048; }
  else { bx -= 416; Ap = Rz; Bp = Wr; Cp = UR; bn = bx & 7; bm = bx >> 3; Nout = 1024; }
  GEMM_KLOOP(Ap, Bp, KS)
  const int crow0 = bm * 128 + wm * 64 + ((lane >> 4) << 2);
  const int ccol0 = bn * 128 + wn * 64 + arow;
  #pragma unroll
  for (int i = 0; i < 4; ++i)
    #pragma unroll
    for (int j = 0; j < 4; ++j) {
      const int col = ccol0 + j * 16;
      #pragma unroll
      for (int r = 0; r < 4; ++r) {
        const int row = crow0 + i * 16 + r;
        float v = acc[i][j][r];
        if (isUF) {
          int bb = row / 810; if (bb > 3) bb = 3;   // clamp padded rows
          v += baseW[(size_t)bb * 2048 + col];
        }
        Cp[(size_t)row * Nout + col] = f2bf(v);
      }
    }
}

// ---------------- combine: h1 = relu(UL'[s] + UC[e+1] - coef*UC[s] + UR[e+1]) ----------------
__global__ __launch_bounds__(512) void k_combine(const unsigned short* __restrict__ UF,
                                                 const unsigned short* __restrict__ UR,
                                                 unsigned short* __restrict__ h1)
{
  __shared__ float s_ul[1024];
  __shared__ float s_ucs[1024];
  const int flat = (blockIdx.x & 7) * 405 + (blockIdx.x >> 3);
  if (flat >= BATCH * T_LEN) return;
  const int b = flat / T_LEN;
  const int s = flat - b * T_LEN;
  const int oct = threadIdx.x >> 6;      // 0..7: eight span-rows in flight
  const int t = threadIdx.x & 63;        // 16-elem slice
  const size_t rs = (size_t)b * 810 + s;
  const int e0 = t * 16;

  {
    const unsigned int u = *(const unsigned int*)(UF + rs * 2048 + threadIdx.x * 2);
    const unsigned int c = *(const unsigned int*)(UF + rs * 2048 + 1024 + threadIdx.x * 2);
    s_ul[threadIdx.x * 2]      = bf2f(u & 0xffff);
    s_ul[threadIdx.x * 2 + 1]  = bf2f(u >> 16);
    s_ucs[threadIdx.x * 2]     = bf2f(c & 0xffff);
    s_ucs[threadIdx.x * 2 + 1] = bf2f(c >> 16);
  }
  __syncthreads();

  float ul[16], ucs[16];
  #pragma unroll
  for (int k = 0; k < 4; ++k) {
    const float4 a = *(const float4*)&s_ul[e0 + k * 4];
    const float4 c = *(const float4*)&s_ucs[e0 + k * 4];
    ul[4*k] = a.x; ul[4*k+1] = a.y; ul[4*k+2] = a.z; ul[4*k+3] = a.w;
    ucs[4*k] = c.x; ucs[4*k+1] = c.y; ucs[4*k+2] = c.z; ucs[4*k+3] = c.w;
  }

  const int nspan = min(16, T_LEN - s);
  int r0;
  if (s < 794) r0 = s * 16;
  else { const int d = s - 794; r0 = 12704 + 15 * d - (d * (d - 1)) / 2; }

  #pragma unroll
  for (int sp = 0; sp < 16; sp += 8) {
    const int row = sp + oct;
    if (row < nspan) {
      const size_t re = rs + row + 1;
      const uint4 e0v = *(const uint4*)(UF + re * 2048 + 1024 + e0);
      const uint4 e1v = *(const uint4*)(UF + re * 2048 + 1024 + e0 + 8);
      const uint4 r0v = *(const uint4*)(UR + re * 1024 + e0);
      const uint4 r1v = *(const uint4*)(UR + re * 1024 + e0 + 8);
      const float c = c_coef[row];
      const unsigned int* pe0 = (const unsigned int*)&e0v;
      const unsigned int* pe1 = (const unsigned int*)&e1v;
      const unsigned int* pr0 = (const unsigned int*)&r0v;
      const unsigned int* pr1 = (const unsigned int*)&r1v;
      unsigned int o[8];
      #pragma unroll
      for (int i = 0; i < 4; ++i) {
        float xlo = ul[2*i]   + bf2f(pe0[i] & 0xffff) - c * ucs[2*i]   + bf2f(pr0[i] & 0xffff);
        float xhi = ul[2*i+1] + bf2f(pe0[i] >> 16)    - c * ucs[2*i+1] + bf2f(pr0[i] >> 16);
        xlo = xlo > 0.f ? xlo : 0.f;
        xhi = xhi > 0.f ? xhi : 0.f;
        o[i] = (unsigned int)f2bf(xlo) | ((unsigned int)f2bf(xhi) << 16);
        float ylo = ul[8+2*i]   + bf2f(pe1[i] & 0xffff) - c * ucs[8+2*i]   + bf2f(pr1[i] & 0xffff);
        float yhi = ul[8+2*i+1] + bf2f(pe1[i] >> 16)    - c * ucs[8+2*i+1] + bf2f(pr1[i] >> 16);
        ylo = ylo > 0.f ? ylo : 0.f;
        yhi = yhi > 0.f ? yhi : 0.f;
        o[4 + i] = (unsigned int)f2bf(ylo) | ((unsigned int)f2bf(yhi) << 16);
      }
      unsigned short* dst = h1 + ((size_t)b * NPAD + r0 + row) * H1 + e0;
      *(uint4*)dst = *(const uint4*)&o[0];
      *(uint4*)(dst + 8) = *(const uint4*)&o[4];
    }
  }
}

// ---------------- GEMM2 + fused W3: R11 best — 128x128, BK=32, 4 blocks/CU ----------------
__global__ __launch_bounds__(256, 4) void k_gemm2p(const unsigned short* __restrict__ A,
                                                   const unsigned short* __restrict__ W2b,
                                                   const float* __restrict__ bias,
                                                   const float* __restrict__ W3,
                                                   float* __restrict__ P)
{
  const int global = blockIdx.x * 202 + blockIdx.y;   // xcd-contiguous bm range, bn fastest
  const int bm = global >> 2;
  const int bn = global & 3;
  __shared__ float red[2][4][4][4][2];                // [wm][i][r][grp][{p0,p1}]
  GEMM_KLOOP(A, W2b, H1)

  const int ccol0 = bn * 128 + wn * 64 + arow;
  float bj[4], w0[4], w1[4];
  #pragma unroll
  for (int j = 0; j < 4; ++j) {
    const int col = ccol0 + j * 16;
    bj[j] = bias[col];
    w0[j] = W3[col];
    w1[j] = W3[H2 + col];
  }
  float p0[4][4], p1[4][4];
  #pragma unroll
  for (int i = 0; i < 4; ++i)
    #pragma unroll
    for (int r = 0; r < 4; ++r) {
      float q0 = 0.f, q1 = 0.f;
      #pragma unroll
      for (int j = 0; j < 4; ++j) {
        float v = acc[i][j][r] + bj[j];
        v = v > 0.f ? v : 0.f;
        q0 = fmaf(v, w0[j], q0);
        q1 = fmaf(v, w1[j], q1);
      }
      #pragma unroll
      for (int m = 1; m < 16; m <<= 1) {
        q0 += __shfl_xor(q0, m);
        q1 += __shfl_xor(q1, m);
      }
      p0[i][r] = q0; p1[i][r] = q1;
    }

  const int grp = lane >> 4;
  if (wn == 1 && arow == 0) {
    #pragma unroll
    for (int i = 0; i < 4; ++i)
      #pragma unroll
      for (int r = 0; r < 4; ++r) {
        red[wm][i][r][grp][0] = p0[i][r];
        red[wm][i][r][grp][1] = p1[i][r];
      }
  }
  __syncthreads();
  if (wn == 0 && arow == 0) {
    #pragma unroll
    for (int i = 0; i < 4; ++i)
      #pragma unroll
      for (int r = 0; r < 4; ++r) {
        const size_t row = (size_t)bm * 128 + wm * 64 + grp * 4 + i * 16 + r;
        P[row * 8 + bn * 2 + 0] = p0[i][r] + red[wm][i][r][grp][0];
        P[row * 8 + bn * 2 + 1] = p1[i][r] + red[wm][i][r][grp][1];
      }
  }
}

// ---------------- final: sum 4 bn-partials per row -> out ----------------
__global__ __launch_bounds__(256) void k_fin(const float* __restrict__ P, float* __restrict__ out)
{
  const int row = blockIdx.x * 256 + threadIdx.x;
  if (row >= MROWS_F) return;
  const int b = row / NPAD;
  const int rr = row - b * NPAD;
  if (rr >= NCAND) return;
  const float4 pa = ((const float4*)P)[row * 2];
  const float4 pb = ((const float4*)P)[row * 2 + 1];
  float* o = out + ((size_t)b * NCAND + rr) * 2;
  o[0] = pa.x + pa.z + pb.x + pb.z;
  o[1] = pa.y + pa.w + pb.y + pb.w;
}

// ---------------- launch ----------------
extern "C" void kernel_launch(void* const* d_in, const int* in_sizes, int n_in,
                              void* d_out, int out_size, void* d_ws, size_t ws_size,
                              hipStream_t stream)
{
  const float* doc = (const float*)d_in[0];
  const float* qe  = (const float*)d_in[1];
  const float* W1  = (const float*)d_in[2];
  const float* g1  = (const float*)d_in[3];
  const float* b1  = (const float*)d_in[4];
  const float* m1  = (const float*)d_in[5];
  const float* v1  = (const float*)d_in[6];
  const float* W2  = (const float*)d_in[7];
  const float* g2  = (const float*)d_in[8];
  const float* b2  = (const float*)d_in[9];
  const float* m2  = (const float*)d_in[10];
  const float* v2  = (const float*)d_in[11];
  const float* W3  = (const float*)d_in[12];
  float* out = (float*)d_out;

  char* ws = (char*)d_ws;
  size_t off = 0;
  auto alloc = [&](size_t bytes) -> void* {
    void* p = ws + off;
    off = (off + bytes + 255) & ~(size_t)255;
    return p;
  };
  unsigned short* Fz    = (unsigned short*)alloc((size_t)TPAD * KS * 2);
  unsigned short* Rz    = (unsigned short*)alloc((size_t)TPAD * KS * 2);
  unsigned short* Wlc   = (unsigned short*)alloc((size_t)2048 * KS * 2);
  unsigned short* Wr    = (unsigned short*)alloc((size_t)1024 * KS * 2);
  unsigned short* W2b   = (unsigned short*)alloc((size_t)H2 * H1 * 2);
  float*          bias2 = (float*)alloc((size_t)H2 * 4);
  float*          baseW = (float*)alloc((size_t)BATCH * 2048 * 4);
  unsigned short* UF    = (unsigned short*)alloc((size_t)TPAD * 2048 * 2);
  unsigned short* UR    = (unsigned short*)alloc((size_t)TPAD * 1024 * 2);
  unsigned short* h1    = (unsigned short*)alloc((size_t)MROWS_F * H1 * 2);
  float*          P     = (float*)alloc((size_t)MROWS_F * 8 * 4);
  (void)ws_size;

  // 1. fused prep (scan + qf/baseW + weight folds)
  k_prep<<<dim3(MP_TOTAL), 256, 0, stream>>>(doc, qe, W1, g1, b1, m1, v1,
                                             W2, g2, b2, m2, v2,
                                             Fz, Rz, Wlc, Wr, W2b, bias2, baseW);
  // 2. fused U-table GEMMs (base folded into UF)
  k_ugemm<<<dim3(416 + 208), 256, 0, stream>>>(Fz, Wlc, Rz, Wr, baseW, UF, UR);
  // 3. gather-combine -> h1 (bf16)
  k_combine<<<dim3(8 * 405), 512, 0, stream>>>(UF, UR, h1);
  // 4. GEMM2 with fused W3 partials (R11 best config)
  k_gemm2p<<<dim3(8, 202), 256, 0, stream>>>(h1, W2b, bias2, W3, P);
  // 5. reduce partials -> out
  k_fin<<<dim3((MROWS_F + 255) / 256), 256, 0, stream>>>(P, out);
}